// Round 4
// baseline (49.122 us; speedup 1.0000x reference)
//
#include <hip/hip_runtime.h>

#define T_ 32
#define N_ 16
#define D_ 256
#define A_ 256
#define F1_ 512
#define F2_ 256
#define M_ (T_ * N_)
#define FS_ 16   // f-strip width in kA  (F1_/FS_ = 32 strips)
#define GS_ 16   // g-strip width in kB  (F2_/GS_ = 16 strips)

typedef float v2f __attribute__((ext_vector_type(2)));

// DPP-based butterfly stage: returns partner lane's value at VALU speed.
// CTRL: 0xB1 = quad_perm[1,0,3,2] (xor-1), 0x4E = quad_perm[2,3,0,1] (xor-2),
//       0x128 = row_ror:8 (== xor-8 within each 16-lane row).
template <int CTRL>
static __device__ __forceinline__ float dpp_partner(float v) {
  int i = __builtin_bit_cast(int, v);
  int p = __builtin_amdgcn_update_dpp(i, i, CTRL, 0xF, 0xF, true);
  return __builtin_bit_cast(float, p);
}

// Full 64-lane sum, bit-identical pairing/order to the shfl_xor butterfly
// (stages ^1,^2,^4,^8,^16,^32). Only ^4 uses the DS pipe.
static __device__ __forceinline__ float wave_allreduce_add(float c) {
  c += dpp_partner<0xB1>(c);          // ^1  (quad_perm, VALU)
  c += dpp_partner<0x4E>(c);          // ^2  (quad_perm, VALU)
  c += __shfl_xor(c, 4, 64);          // ^4  (DS)
  c += dpp_partner<0x128>(c);         // ^8  (row_ror:8, VALU)
  {                                    // ^16 (v_permlane16_swap, VALU)
    float a = c, b = c;
    asm("v_permlane16_swap_b32 %0, %1" : "+v"(a), "+v"(b));
    c = a + b;
  }
  {                                    // ^32 (v_permlane32_swap, VALU)
    float a = c, b = c;
    asm("v_permlane32_swap_b32 %0, %1" : "+v"(a), "+v"(b));
    c = a + b;
  }
  return c;
}

// -------- Kernel 1: SDC linear + exp_filter + LIF1 + synapse filter +
//          pool over A + LIF2 (s2), fused. One wave per (n,d).
//          Packed-f32 elementwise chains; DPP/permlane pool reduction. ------
__global__ __launch_bounds__(64) void k1_sdc(const float* __restrict__ x,
    const float* __restrict__ Wsdc, const float* __restrict__ bsdc,
    const float* __restrict__ wsyn, const float* __restrict__ Wpool,
    const float* __restrict__ bpool, float* __restrict__ s2) {
  const int blk = blockIdx.x;      // n*256 + d
  const int n = blk >> 8;
  const int d = blk & 255;
  const int lane = threadIdx.x;    // 0..63

  const float syn_decay = 1.0f - 1.0f / (1.0f + expf(-wsyn[0]));
  const float bp = bpool[0];

  // a-pairs: P0 = {lane, lane+64}, P1 = {lane+128, lane+192}
  v2f w0a, w0b, w1a, w1b, baa, bab, wpa, wpb;
  w0a.x = Wsdc[lane];        w0a.y = Wsdc[lane + 64];
  w0b.x = Wsdc[lane + 128];  w0b.y = Wsdc[lane + 192];
  w1a.x = Wsdc[A_ + lane];       w1a.y = Wsdc[A_ + lane + 64];
  w1b.x = Wsdc[A_ + lane + 128]; w1b.y = Wsdc[A_ + lane + 192];
  baa.x = bsdc[lane];        baa.y = bsdc[lane + 64];
  bab.x = bsdc[lane + 128];  bab.y = bsdc[lane + 192];
  wpa.x = Wpool[lane];       wpa.y = Wpool[lane + 64];
  wpb.x = Wpool[lane + 128]; wpb.y = Wpool[lane + 192];

  v2f cura = {0.f, 0.f}, curb = {0.f, 0.f};
  v2f vma  = {0.f, 0.f}, vmb  = {0.f, 0.f};
  v2f syna = {0.f, 0.f}, synb = {0.f, 0.f};
  v2f sdv; sdv.x = syn_decay; sdv.y = syn_decay;
  float v2 = 0.0f;
  float s2v = 0.0f;   // lane t holds spike for time t (t<32)

#pragma unroll 8
  for (int t = 0; t < T_; ++t) {
    // wave-uniform x loads (scalarizable by compiler)
    const float x0 = x[((t * N_ + n) * 2 + 0) * D_ + d];
    const float x1 = x[((t * N_ + n) * 2 + 1) * D_ + d];

    // elementwise LIF chains, per-component identical to scalar version
    v2f ha = x0 * w0a + x1 * w1a + baa;
    v2f hb = x0 * w0b + x1 * w1b + bab;
    cura = cura * 0.5f + ha;
    curb = curb * 0.5f + hb;
    v2f va = vma + (cura - vma) * 0.5f;
    v2f vb = vmb + (curb - vmb) * 0.5f;
    const bool sp0 = (va.x >= 1.0f), sp1 = (va.y >= 1.0f);
    const bool sp2 = (vb.x >= 1.0f), sp3 = (vb.y >= 1.0f);
    v2f spa, spb;
    spa.x = sp0 ? 1.0f : 0.0f; spa.y = sp1 ? 1.0f : 0.0f;
    spb.x = sp2 ? 1.0f : 0.0f; spb.y = sp3 ? 1.0f : 0.0f;
    syna = syna * sdv + spa;
    synb = synb * sdv + spb;
    vma.x = sp0 ? 0.0f : va.x; vma.y = sp1 ? 0.0f : va.y;
    vmb.x = sp2 ? 0.0f : vb.x; vmb.y = sp3 ? 0.0f : vb.y;

    // pool partial: scalar, SAME j-order (0,1,2,3)
    float c = 0.0f;
    c += syna.x * wpa.x;
    c += syna.y * wpa.y;
    c += synb.x * wpb.x;
    c += synb.y * wpb.y;
    c = wave_allreduce_add(c);        // bit-identical to shfl_xor butterfly

    const float z = c + bp;
    v2 = v2 + (z - v2) * 0.5f;                    // LIF2
    const bool spk = (v2 >= 1.0f);
    s2v = (lane == t) ? (spk ? 1.0f : 0.0f) : s2v;
    v2 = spk ? 0.0f : v2;
  }
  if (lane < T_) s2[(lane * N_ + n) * D_ + d] = s2v;
}

// -------- Kernel A: fused GEMM1 + bias + LIF scan. Per-chunk weight
//          prefetch into registers. Block = (n, f-strip of 16). ------------
__global__ __launch_bounds__(256) void kA_gemm1(const float* __restrict__ s2,
    const float* __restrict__ Wf1, const float* __restrict__ bf1,
    float* __restrict__ h1, float* __restrict__ partial, int* __restrict__ cnt) {
  __shared__ __align__(16) float s2l[T_ * 260];   // rows padded 256->260
  __shared__ __align__(16) float g1l[T_ * FS_];
  const int bx = blockIdx.x;
  const int n = bx >> 5, fs = bx & 31;
  const int tid = threadIdx.x;

  if (bx == 0) {   // zero kB's cross-block accumulators (fill re-poisons ws)
    partial[tid] = 0.0f;
    partial[tid + 256] = 0.0f;
    if (tid < N_) cnt[tid] = 0;
  }

  {  // stage s2[:, n, :] -> LDS (float4, padded rows)
    const float4* g4 = (const float4*)s2;
    float4* l4 = (float4*)s2l;
#pragma unroll
    for (int r = 0; r < 8; ++r) {
      const int i4 = r * 256 + tid;
      const int t = i4 >> 6, dq = i4 & 63;
      l4[t * 65 + dq] = g4[(t * N_ + n) * 64 + dq];
    }
  }
  __syncthreads();

  const int f = tid & 15, tg = tid >> 4;
  const float* wc = Wf1 + fs * FS_ + f;
  float acc[2][4] = {};
#pragma unroll
  for (int kc = 0; kc < 4; ++kc) {   // split-K chunks: identical order
    float w[64];                     // batched weight prefetch (registers)
#pragma unroll
    for (int k = 0; k < 64; ++k) w[k] = wc[(kc * 64 + k) * F1_];
#pragma unroll
    for (int d0 = 0; d0 < 64; d0 += 4) {
#pragma unroll
      for (int j = 0; j < 2; ++j) {
        const float4 sv = *(const float4*)&s2l[(tg * 2 + j) * 260 + kc * 64 + d0];
        acc[j][kc] += sv.x * w[d0 + 0]; acc[j][kc] += sv.y * w[d0 + 1];
        acc[j][kc] += sv.z * w[d0 + 2]; acc[j][kc] += sv.w * w[d0 + 3];
      }
    }
  }
  const float b = bf1[fs * FS_ + f];
#pragma unroll
  for (int j = 0; j < 2; ++j) {
    float g = b;
    g += acc[j][0]; g += acc[j][1]; g += acc[j][2]; g += acc[j][3];
    g1l[(tg * 2 + j) * FS_ + f] = g;
  }
  __syncthreads();

  if (tid < FS_) {   // LIF scan over t (identical expressions)
    float v = 0.0f;
#pragma unroll
    for (int t = 0; t < T_; ++t) {
      const float g = g1l[t * FS_ + tid];
      v = v + (g - v) * 0.5f;
      const bool sp = (v >= 1.0f);
      h1[(t * N_ + n) * F1_ + fs * FS_ + tid] = sp ? 1.0f : 0.0f;
      v = sp ? 0.0f : v;
    }
  }
}

// -------- Kernel B: fused GEMM2 + bias + LIF scan + W_out pool + cumsum.
//          GS=16, 256 blocks, per-chunk weight prefetch. Last block per n
//          (16 strips) finishes pool + cumsum. ----------------------------
__global__ __launch_bounds__(256) void kB_gemm2(const float* __restrict__ h1,
    const float* __restrict__ Wf2, const float* __restrict__ bf2,
    const float* __restrict__ Wout, const float* __restrict__ bout,
    float* __restrict__ partial, int* __restrict__ cnt, float* __restrict__ out) {
  __shared__ __align__(16) float h1l[T_ * 516];   // rows padded 512->516
  __shared__ __align__(16) float g2l[T_ * GS_];
  __shared__ __align__(16) float h2l[T_ * GS_];
  __shared__ int lastFlag;
  const int bx = blockIdx.x;
  const int n = bx >> 4, gs = bx & 15;
  const int tid = threadIdx.x;

  {  // stage h1[:, n, :] -> LDS (float4, padded rows)
    const float4* g4 = (const float4*)h1;
    float4* l4 = (float4*)h1l;
#pragma unroll
    for (int r = 0; r < 16; ++r) {
      const int i4 = r * 256 + tid;
      const int t = i4 >> 7, fq = i4 & 127;
      l4[t * 129 + fq] = g4[(t * N_ + n) * 128 + fq];
    }
  }
  __syncthreads();

  const int g = tid & 15, tg = tid >> 4;
  const float* wc = Wf2 + gs * GS_ + g;
  float acc[2][8] = {};
#pragma unroll
  for (int kc = 0; kc < 8; ++kc) {   // identical split-K order
    float w[64];                     // batched weight prefetch (registers)
#pragma unroll
    for (int k = 0; k < 64; ++k) w[k] = wc[(kc * 64 + k) * F2_];
#pragma unroll
    for (int d0 = 0; d0 < 64; d0 += 4) {
#pragma unroll
      for (int j = 0; j < 2; ++j) {
        const float4 hv = *(const float4*)&h1l[(tg * 2 + j) * 516 + kc * 64 + d0];
        acc[j][kc] += hv.x * w[d0 + 0]; acc[j][kc] += hv.y * w[d0 + 1];
        acc[j][kc] += hv.z * w[d0 + 2]; acc[j][kc] += hv.w * w[d0 + 3];
      }
    }
  }
  const float b = bf2[gs * GS_ + g];
#pragma unroll
  for (int j = 0; j < 2; ++j) {
    float z = b;
#pragma unroll
    for (int kc = 0; kc < 8; ++kc) z += acc[j][kc];
    g2l[(tg * 2 + j) * GS_ + g] = z;
  }
  __syncthreads();

  if (tid < GS_) {   // LIF scan (identical expressions)
    float v = 0.0f;
#pragma unroll
    for (int t = 0; t < T_; ++t) {
      const float gv = g2l[t * GS_ + tid];
      v = v + (gv - v) * 0.5f;
      const bool sp = (v >= 1.0f);
      h2l[t * GS_ + tid] = sp ? 1.0f : 0.0f;
      v = sp ? 0.0f : v;
    }
  }
  __syncthreads();

  if (tid < T_) {    // per-strip partial pool (post-spike: reorder harmless)
    float pp = 0.0f;
#pragma unroll
    for (int j2 = 0; j2 < GS_; ++j2)
      pp += h2l[tid * GS_ + j2] * Wout[gs * GS_ + j2];
    __hip_atomic_fetch_add(&partial[tid * N_ + n], pp,
                           __ATOMIC_RELAXED, __HIP_MEMORY_SCOPE_AGENT);
  }
  __syncthreads();   // this block's atomics are issued & drained

  if (tid == 0) {
    __threadfence();
    const int old = __hip_atomic_fetch_add(&cnt[n], 1,
                        __ATOMIC_ACQ_REL, __HIP_MEMORY_SCOPE_AGENT);
    lastFlag = (old == 15);
  }
  __syncthreads();

  if (lastFlag && tid < T_) {  // last block for this n: finish pool + cumsum
    float val = __hip_atomic_load(&partial[tid * N_ + n],
                    __ATOMIC_RELAXED, __HIP_MEMORY_SCOPE_AGENT) + bout[0];
#pragma unroll
    for (int off = 1; off < 32; off <<= 1) {   // inclusive prefix over t
      const float up = __shfl_up(val, off, 64);
      if (tid >= off) val += up;
    }
    out[tid * N_ + n] = val;
  }
}

extern "C" void kernel_launch(void* const* d_in, const int* in_sizes, int n_in,
                              void* d_out, int out_size, void* d_ws, size_t ws_size,
                              hipStream_t stream) {
  (void)in_sizes; (void)n_in; (void)out_size; (void)ws_size;
  const float* x     = (const float*)d_in[0];
  const float* Wsdc  = (const float*)d_in[1];
  const float* bsdc  = (const float*)d_in[2];
  const float* wsyn  = (const float*)d_in[3];
  const float* Wpool = (const float*)d_in[4];
  const float* bpool = (const float*)d_in[5];
  const float* Wf1   = (const float*)d_in[6];
  const float* bf1   = (const float*)d_in[7];
  const float* Wf2   = (const float*)d_in[8];
  const float* bf2   = (const float*)d_in[9];
  const float* Wout  = (const float*)d_in[10];
  const float* bout  = (const float*)d_in[11];
  float* out = (float*)d_out;

  // ws layout (floats): s2[M*D] | h1[M*F1] | partial[T*N] | cnt[N]
  float* s2      = (float*)d_ws;
  float* h1      = s2 + M_ * D_;
  float* partial = h1 + M_ * F1_;
  int*   cnt     = (int*)(partial + T_ * N_);

  hipLaunchKernelGGL(k1_sdc, dim3(N_ * D_), dim3(64), 0, stream,
                     x, Wsdc, bsdc, wsyn, Wpool, bpool, s2);
  hipLaunchKernelGGL(kA_gemm1, dim3(N_ * (F1_ / FS_)), dim3(256), 0, stream,
                     s2, Wf1, bf1, h1, partial, cnt);
  hipLaunchKernelGGL(kB_gemm2, dim3(N_ * (F2_ / GS_)), dim3(256), 0, stream,
                     h1, Wf2, bf2, Wout, bout, partial, cnt, out);
}

// Round 5
// 48.570 us; speedup vs baseline: 1.0114x; 1.0114x over previous
//
#include <hip/hip_runtime.h>

#define T_ 32
#define N_ 16
#define D_ 256
#define A_ 256
#define F1_ 512
#define F2_ 256
#define M_ (T_ * N_)
#define FS_ 16   // f-strip width in kA  (F1_/FS_ = 32 strips)
#define GS_ 16   // g-strip width in kB  (F2_/GS_ = 16 strips)

typedef float v2f __attribute__((ext_vector_type(2)));

// -------- Kernel 1: SDC linear + exp_filter + LIF1 + synapse filter +
//          pool over A + LIF2 (s2), fused. One wave per (n,d).
//          Packed-f32 elementwise chains; wave-uniform x loads.
//          (R3 measured-best form, unchanged.) ----------------------------
__global__ __launch_bounds__(64) void k1_sdc(const float* __restrict__ x,
    const float* __restrict__ Wsdc, const float* __restrict__ bsdc,
    const float* __restrict__ wsyn, const float* __restrict__ Wpool,
    const float* __restrict__ bpool, float* __restrict__ s2) {
  const int blk = blockIdx.x;      // n*256 + d
  const int n = blk >> 8;
  const int d = blk & 255;
  const int lane = threadIdx.x;    // 0..63

  const float syn_decay = 1.0f - 1.0f / (1.0f + expf(-wsyn[0]));
  const float bp = bpool[0];

  // a-pairs: P0 = {lane, lane+64}, P1 = {lane+128, lane+192}
  v2f w0a, w0b, w1a, w1b, baa, bab, wpa, wpb;
  w0a.x = Wsdc[lane];        w0a.y = Wsdc[lane + 64];
  w0b.x = Wsdc[lane + 128];  w0b.y = Wsdc[lane + 192];
  w1a.x = Wsdc[A_ + lane];       w1a.y = Wsdc[A_ + lane + 64];
  w1b.x = Wsdc[A_ + lane + 128]; w1b.y = Wsdc[A_ + lane + 192];
  baa.x = bsdc[lane];        baa.y = bsdc[lane + 64];
  bab.x = bsdc[lane + 128];  bab.y = bsdc[lane + 192];
  wpa.x = Wpool[lane];       wpa.y = Wpool[lane + 64];
  wpb.x = Wpool[lane + 128]; wpb.y = Wpool[lane + 192];

  v2f cura = {0.f, 0.f}, curb = {0.f, 0.f};
  v2f vma  = {0.f, 0.f}, vmb  = {0.f, 0.f};
  v2f syna = {0.f, 0.f}, synb = {0.f, 0.f};
  v2f sdv; sdv.x = syn_decay; sdv.y = syn_decay;
  float v2 = 0.0f;
  float s2v = 0.0f;   // lane t holds spike for time t (t<32)

#pragma unroll 8
  for (int t = 0; t < T_; ++t) {
    // wave-uniform x loads (scalarizable by compiler)
    const float x0 = x[((t * N_ + n) * 2 + 0) * D_ + d];
    const float x1 = x[((t * N_ + n) * 2 + 1) * D_ + d];

    // elementwise LIF chains, per-component identical to scalar version
    v2f ha = x0 * w0a + x1 * w1a + baa;
    v2f hb = x0 * w0b + x1 * w1b + bab;
    cura = cura * 0.5f + ha;
    curb = curb * 0.5f + hb;
    v2f va = vma + (cura - vma) * 0.5f;
    v2f vb = vmb + (curb - vmb) * 0.5f;
    const bool sp0 = (va.x >= 1.0f), sp1 = (va.y >= 1.0f);
    const bool sp2 = (vb.x >= 1.0f), sp3 = (vb.y >= 1.0f);
    v2f spa, spb;
    spa.x = sp0 ? 1.0f : 0.0f; spa.y = sp1 ? 1.0f : 0.0f;
    spb.x = sp2 ? 1.0f : 0.0f; spb.y = sp3 ? 1.0f : 0.0f;
    syna = syna * sdv + spa;
    synb = synb * sdv + spb;
    vma.x = sp0 ? 0.0f : va.x; vma.y = sp1 ? 0.0f : va.y;
    vmb.x = sp2 ? 0.0f : vb.x; vmb.y = sp3 ? 0.0f : vb.y;

    // pool partial: scalar, SAME j-order (0,1,2,3)
    float c = 0.0f;
    c += syna.x * wpa.x;
    c += syna.y * wpa.y;
    c += synb.x * wpb.x;
    c += synb.y * wpb.y;
#pragma unroll
    for (int m = 1; m < 64; m <<= 1) c += __shfl_xor(c, m, 64);

    const float z = c + bp;
    v2 = v2 + (z - v2) * 0.5f;                    // LIF2
    const bool spk = (v2 >= 1.0f);
    s2v = (lane == t) ? (spk ? 1.0f : 0.0f) : s2v;
    v2 = spk ? 0.0f : v2;
  }
  if (lane < T_) s2[(lane * N_ + n) * D_ + d] = s2v;
}

// Double-buffered weight prefetch macros (literal chunk indices -> all
// register indices compile-time; FP order identical to single-buffer form).
#define KA_LOAD(buf, KC)                                        \
  _Pragma("unroll")                                             \
  for (int k = 0; k < 64; ++k) buf[k] = wc[((KC) * 64 + k) * F1_];
#define KA_COMP(buf, KC)                                        \
  _Pragma("unroll")                                             \
  for (int d0 = 0; d0 < 64; d0 += 4) {                          \
    _Pragma("unroll")                                           \
    for (int j = 0; j < 2; ++j) {                               \
      const float4 sv =                                         \
        *(const float4*)&s2l[(tg * 2 + j) * 260 + (KC) * 64 + d0]; \
      acc[j][KC] += sv.x * buf[d0 + 0];                         \
      acc[j][KC] += sv.y * buf[d0 + 1];                         \
      acc[j][KC] += sv.z * buf[d0 + 2];                         \
      acc[j][KC] += sv.w * buf[d0 + 3];                         \
    }                                                           \
  }

// -------- Kernel A: fused GEMM1 + bias + LIF scan. Double-buffered weight
//          prefetch (chunk kc+1 loads issued before chunk kc compute). -----
__global__ __launch_bounds__(256) void kA_gemm1(const float* __restrict__ s2,
    const float* __restrict__ Wf1, const float* __restrict__ bf1,
    float* __restrict__ h1, float* __restrict__ partial, int* __restrict__ cnt) {
  __shared__ __align__(16) float s2l[T_ * 260];   // rows padded 256->260
  __shared__ __align__(16) float g1l[T_ * FS_];
  const int bx = blockIdx.x;
  const int n = bx >> 5, fs = bx & 31;
  const int tid = threadIdx.x;

  if (bx == 0) {   // zero kB's cross-block accumulators (fill re-poisons ws)
    partial[tid] = 0.0f;
    partial[tid + 256] = 0.0f;
    if (tid < N_) cnt[tid] = 0;
  }

  {  // stage s2[:, n, :] -> LDS (float4, padded rows)
    const float4* g4 = (const float4*)s2;
    float4* l4 = (float4*)s2l;
#pragma unroll
    for (int r = 0; r < 8; ++r) {
      const int i4 = r * 256 + tid;
      const int t = i4 >> 6, dq = i4 & 63;
      l4[t * 65 + dq] = g4[(t * N_ + n) * 64 + dq];
    }
  }
  __syncthreads();

  const int f = tid & 15, tg = tid >> 4;
  const float* wc = Wf1 + fs * FS_ + f;
  float acc[2][4] = {};
  float wA[64], wB[64];
  KA_LOAD(wA, 0)
  KA_LOAD(wB, 1)          // prefetch chunk 1
  KA_COMP(wA, 0)
  KA_LOAD(wA, 2)          // prefetch chunk 2
  KA_COMP(wB, 1)
  KA_LOAD(wB, 3)          // prefetch chunk 3
  KA_COMP(wA, 2)
  KA_COMP(wB, 3)

  const float b = bf1[fs * FS_ + f];
#pragma unroll
  for (int j = 0; j < 2; ++j) {
    float g = b;
    g += acc[j][0]; g += acc[j][1]; g += acc[j][2]; g += acc[j][3];
    g1l[(tg * 2 + j) * FS_ + f] = g;
  }
  __syncthreads();

  if (tid < FS_) {   // LIF scan over t (identical expressions)
    float v = 0.0f;
#pragma unroll
    for (int t = 0; t < T_; ++t) {
      const float g = g1l[t * FS_ + tid];
      v = v + (g - v) * 0.5f;
      const bool sp = (v >= 1.0f);
      h1[(t * N_ + n) * F1_ + fs * FS_ + tid] = sp ? 1.0f : 0.0f;
      v = sp ? 0.0f : v;
    }
  }
}

#define KB_LOAD(buf, KC)                                        \
  _Pragma("unroll")                                             \
  for (int k = 0; k < 64; ++k) buf[k] = wc[((KC) * 64 + k) * F2_];
#define KB_COMP(buf, KC)                                        \
  _Pragma("unroll")                                             \
  for (int d0 = 0; d0 < 64; d0 += 4) {                          \
    _Pragma("unroll")                                           \
    for (int j = 0; j < 2; ++j) {                               \
      const float4 hv =                                         \
        *(const float4*)&h1l[(tg * 2 + j) * 516 + (KC) * 64 + d0]; \
      acc[j][KC] += hv.x * buf[d0 + 0];                         \
      acc[j][KC] += hv.y * buf[d0 + 1];                         \
      acc[j][KC] += hv.z * buf[d0 + 2];                         \
      acc[j][KC] += hv.w * buf[d0 + 3];                         \
    }                                                           \
  }

// -------- Kernel B: fused GEMM2 + bias + LIF scan + W_out pool + cumsum.
//          GS=16, 256 blocks, double-buffered weight prefetch. Last block
//          per n (16 strips) finishes pool + cumsum. ----------------------
__global__ __launch_bounds__(256) void kB_gemm2(const float* __restrict__ h1,
    const float* __restrict__ Wf2, const float* __restrict__ bf2,
    const float* __restrict__ Wout, const float* __restrict__ bout,
    float* __restrict__ partial, int* __restrict__ cnt, float* __restrict__ out) {
  __shared__ __align__(16) float h1l[T_ * 516];   // rows padded 512->516
  __shared__ __align__(16) float g2l[T_ * GS_];
  __shared__ __align__(16) float h2l[T_ * GS_];
  __shared__ int lastFlag;
  const int bx = blockIdx.x;
  const int n = bx >> 4, gs = bx & 15;
  const int tid = threadIdx.x;

  {  // stage h1[:, n, :] -> LDS (float4, padded rows)
    const float4* g4 = (const float4*)h1;
    float4* l4 = (float4*)h1l;
#pragma unroll
    for (int r = 0; r < 16; ++r) {
      const int i4 = r * 256 + tid;
      const int t = i4 >> 7, fq = i4 & 127;
      l4[t * 129 + fq] = g4[(t * N_ + n) * 128 + fq];
    }
  }
  __syncthreads();

  const int g = tid & 15, tg = tid >> 4;
  const float* wc = Wf2 + gs * GS_ + g;
  float acc[2][8] = {};
  float wA[64], wB[64];
  KB_LOAD(wA, 0)
  KB_LOAD(wB, 1)          // prefetch chunk 1
  KB_COMP(wA, 0)
  KB_LOAD(wA, 2)
  KB_COMP(wB, 1)
  KB_LOAD(wB, 3)
  KB_COMP(wA, 2)
  KB_LOAD(wA, 4)
  KB_COMP(wB, 3)
  KB_LOAD(wB, 5)
  KB_COMP(wA, 4)
  KB_LOAD(wA, 6)
  KB_COMP(wB, 5)
  KB_LOAD(wB, 7)
  KB_COMP(wA, 6)
  KB_COMP(wB, 7)

  const float b = bf2[gs * GS_ + g];
#pragma unroll
  for (int j = 0; j < 2; ++j) {
    float z = b;
#pragma unroll
    for (int kc = 0; kc < 8; ++kc) z += acc[j][kc];
    g2l[(tg * 2 + j) * GS_ + g] = z;
  }
  __syncthreads();

  if (tid < GS_) {   // LIF scan (identical expressions)
    float v = 0.0f;
#pragma unroll
    for (int t = 0; t < T_; ++t) {
      const float gv = g2l[t * GS_ + tid];
      v = v + (gv - v) * 0.5f;
      const bool sp = (v >= 1.0f);
      h2l[t * GS_ + tid] = sp ? 1.0f : 0.0f;
      v = sp ? 0.0f : v;
    }
  }
  __syncthreads();

  if (tid < T_) {    // per-strip partial pool (post-spike: reorder harmless)
    float pp = 0.0f;
#pragma unroll
    for (int j2 = 0; j2 < GS_; ++j2)
      pp += h2l[tid * GS_ + j2] * Wout[gs * GS_ + j2];
    __hip_atomic_fetch_add(&partial[tid * N_ + n], pp,
                           __ATOMIC_RELAXED, __HIP_MEMORY_SCOPE_AGENT);
  }
  __syncthreads();   // this block's atomics are issued & drained

  if (tid == 0) {
    __threadfence();
    const int old = __hip_atomic_fetch_add(&cnt[n], 1,
                        __ATOMIC_ACQ_REL, __HIP_MEMORY_SCOPE_AGENT);
    lastFlag = (old == 15);
  }
  __syncthreads();

  if (lastFlag && tid < T_) {  // last block for this n: finish pool + cumsum
    float val = __hip_atomic_load(&partial[tid * N_ + n],
                    __ATOMIC_RELAXED, __HIP_MEMORY_SCOPE_AGENT) + bout[0];
#pragma unroll
    for (int off = 1; off < 32; off <<= 1) {   // inclusive prefix over t
      const float up = __shfl_up(val, off, 64);
      if (tid >= off) val += up;
    }
    out[tid * N_ + n] = val;
  }
}

extern "C" void kernel_launch(void* const* d_in, const int* in_sizes, int n_in,
                              void* d_out, int out_size, void* d_ws, size_t ws_size,
                              hipStream_t stream) {
  (void)in_sizes; (void)n_in; (void)out_size; (void)ws_size;
  const float* x     = (const float*)d_in[0];
  const float* Wsdc  = (const float*)d_in[1];
  const float* bsdc  = (const float*)d_in[2];
  const float* wsyn  = (const float*)d_in[3];
  const float* Wpool = (const float*)d_in[4];
  const float* bpool = (const float*)d_in[5];
  const float* Wf1   = (const float*)d_in[6];
  const float* bf1   = (const float*)d_in[7];
  const float* Wf2   = (const float*)d_in[8];
  const float* bf2   = (const float*)d_in[9];
  const float* Wout  = (const float*)d_in[10];
  const float* bout  = (const float*)d_in[11];
  float* out = (float*)d_out;

  // ws layout (floats): s2[M*D] | h1[M*F1] | partial[T*N] | cnt[N]
  float* s2      = (float*)d_ws;
  float* h1      = s2 + M_ * D_;
  float* partial = h1 + M_ * F1_;
  int*   cnt     = (int*)(partial + T_ * N_);

  hipLaunchKernelGGL(k1_sdc, dim3(N_ * D_), dim3(64), 0, stream,
                     x, Wsdc, bsdc, wsyn, Wpool, bpool, s2);
  hipLaunchKernelGGL(kA_gemm1, dim3(N_ * (F1_ / FS_)), dim3(256), 0, stream,
                     s2, Wf1, bf1, h1, partial, cnt);
  hipLaunchKernelGGL(kB_gemm2, dim3(N_ * (F2_ / GS_)), dim3(256), 0, stream,
                     h1, Wf2, bf2, Wout, bout, partial, cnt, out);
}

// Round 6
// 43.399 us; speedup vs baseline: 1.1319x; 1.1192x over previous
//
#include <hip/hip_runtime.h>

#define T_ 32
#define N_ 16
#define D_ 256
#define A_ 256
#define F1_ 512
#define F2_ 256
#define M_ (T_ * N_)
#define FS_ 16   // f-strip width in kA  (F1_/FS_ = 32 strips)
#define GS_ 16   // g-strip width in kB  (F2_/GS_ = 16 strips)

typedef float v2f __attribute__((ext_vector_type(2)));

// -------- Kernel 1: SDC linear + exp_filter + LIF1 + synapse filter +
//          pool over A + LIF2 (s2), fused. One wave per (n,d).
//          (R3 measured-best form, unchanged.) ----------------------------
__global__ __launch_bounds__(64) void k1_sdc(const float* __restrict__ x,
    const float* __restrict__ Wsdc, const float* __restrict__ bsdc,
    const float* __restrict__ wsyn, const float* __restrict__ Wpool,
    const float* __restrict__ bpool, float* __restrict__ s2) {
  const int blk = blockIdx.x;      // n*256 + d
  const int n = blk >> 8;
  const int d = blk & 255;
  const int lane = threadIdx.x;    // 0..63

  const float syn_decay = 1.0f - 1.0f / (1.0f + expf(-wsyn[0]));
  const float bp = bpool[0];

  // a-pairs: P0 = {lane, lane+64}, P1 = {lane+128, lane+192}
  v2f w0a, w0b, w1a, w1b, baa, bab, wpa, wpb;
  w0a.x = Wsdc[lane];        w0a.y = Wsdc[lane + 64];
  w0b.x = Wsdc[lane + 128];  w0b.y = Wsdc[lane + 192];
  w1a.x = Wsdc[A_ + lane];       w1a.y = Wsdc[A_ + lane + 64];
  w1b.x = Wsdc[A_ + lane + 128]; w1b.y = Wsdc[A_ + lane + 192];
  baa.x = bsdc[lane];        baa.y = bsdc[lane + 64];
  bab.x = bsdc[lane + 128];  bab.y = bsdc[lane + 192];
  wpa.x = Wpool[lane];       wpa.y = Wpool[lane + 64];
  wpb.x = Wpool[lane + 128]; wpb.y = Wpool[lane + 192];

  v2f cura = {0.f, 0.f}, curb = {0.f, 0.f};
  v2f vma  = {0.f, 0.f}, vmb  = {0.f, 0.f};
  v2f syna = {0.f, 0.f}, synb = {0.f, 0.f};
  v2f sdv; sdv.x = syn_decay; sdv.y = syn_decay;
  float v2 = 0.0f;
  float s2v = 0.0f;   // lane t holds spike for time t (t<32)

#pragma unroll 8
  for (int t = 0; t < T_; ++t) {
    // wave-uniform x loads (scalarizable by compiler)
    const float x0 = x[((t * N_ + n) * 2 + 0) * D_ + d];
    const float x1 = x[((t * N_ + n) * 2 + 1) * D_ + d];

    // elementwise LIF chains, per-component identical to scalar version
    v2f ha = x0 * w0a + x1 * w1a + baa;
    v2f hb = x0 * w0b + x1 * w1b + bab;
    cura = cura * 0.5f + ha;
    curb = curb * 0.5f + hb;
    v2f va = vma + (cura - vma) * 0.5f;
    v2f vb = vmb + (curb - vmb) * 0.5f;
    const bool sp0 = (va.x >= 1.0f), sp1 = (va.y >= 1.0f);
    const bool sp2 = (vb.x >= 1.0f), sp3 = (vb.y >= 1.0f);
    v2f spa, spb;
    spa.x = sp0 ? 1.0f : 0.0f; spa.y = sp1 ? 1.0f : 0.0f;
    spb.x = sp2 ? 1.0f : 0.0f; spb.y = sp3 ? 1.0f : 0.0f;
    syna = syna * sdv + spa;
    synb = synb * sdv + spb;
    vma.x = sp0 ? 0.0f : va.x; vma.y = sp1 ? 0.0f : va.y;
    vmb.x = sp2 ? 0.0f : vb.x; vmb.y = sp3 ? 0.0f : vb.y;

    // pool partial: scalar, SAME j-order (0,1,2,3)
    float c = 0.0f;
    c += syna.x * wpa.x;
    c += syna.y * wpa.y;
    c += synb.x * wpb.x;
    c += synb.y * wpb.y;
#pragma unroll
    for (int m = 1; m < 64; m <<= 1) c += __shfl_xor(c, m, 64);

    const float z = c + bp;
    v2 = v2 + (z - v2) * 0.5f;                    // LIF2
    const bool spk = (v2 >= 1.0f);
    s2v = (lane == t) ? (spk ? 1.0f : 0.0f) : s2v;
    v2 = spk ? 0.0f : v2;
  }
  if (lane < T_) s2[(lane * N_ + n) * D_ + d] = s2v;
}

// -------- Kernel A: fused GEMM1 + bias + LIF scan. Weight strip staged in
//          LDS transposed [f][k] (removes 16x-redundant global loads).
//          Block = (n, f-strip of 16); 16 f x 16 tg x 2 t. ----------------
__global__ __launch_bounds__(256) void kA_gemm1(const float* __restrict__ s2,
    const float* __restrict__ Wf1, const float* __restrict__ bf1,
    float* __restrict__ h1, float* __restrict__ partial, int* __restrict__ cnt) {
  __shared__ __align__(16) float s2l[T_ * 260];   // rows padded 256->260
  __shared__ __align__(16) float wl[FS_ * 260];   // W^T strip [f][k], pad 260
  __shared__ __align__(16) float g1l[T_ * FS_];
  const int bx = blockIdx.x;
  const int n = bx >> 5, fs = bx & 31;
  const int tid = threadIdx.x;

  if (bx == 0) {   // zero kB's cross-block accumulators (fill re-poisons ws)
    partial[tid] = 0.0f;
    partial[tid + 256] = 0.0f;
    if (tid < N_) cnt[tid] = 0;
  }

  {  // stage s2[:, n, :] -> LDS (float4, padded rows)
    const float4* g4 = (const float4*)s2;
    float4* l4 = (float4*)s2l;
#pragma unroll
    for (int r = 0; r < 8; ++r) {
      const int i4 = r * 256 + tid;
      const int t = i4 >> 6, dq = i4 & 63;
      l4[t * 65 + dq] = g4[(t * N_ + n) * 64 + dq];
    }
  }
  {  // stage Wf1 strip [256 k][16 f] -> wl[f][k] (transposed)
    const int c4 = (tid & 3) << 2, kb = tid >> 2;   // kb 0..63
#pragma unroll
    for (int r = 0; r < 4; ++r) {
      const int k = r * 64 + kb;
      const float4 wv = *(const float4*)&Wf1[k * F1_ + fs * FS_ + c4];
      wl[(c4 + 0) * 260 + k] = wv.x;
      wl[(c4 + 1) * 260 + k] = wv.y;
      wl[(c4 + 2) * 260 + k] = wv.z;
      wl[(c4 + 3) * 260 + k] = wv.w;
    }
  }
  __syncthreads();

  const int f = tid & 15, tg = tid >> 4;
  float acc[2][4] = {};
#pragma unroll
  for (int kc = 0; kc < 4; ++kc) {   // split-K chunks: identical FMA order
#pragma unroll
    for (int d0 = 0; d0 < 64; d0 += 4) {
      const float4 w4 = *(const float4*)&wl[f * 260 + kc * 64 + d0];
#pragma unroll
      for (int j = 0; j < 2; ++j) {
        const float4 sv = *(const float4*)&s2l[(tg * 2 + j) * 260 + kc * 64 + d0];
        acc[j][kc] += sv.x * w4.x; acc[j][kc] += sv.y * w4.y;
        acc[j][kc] += sv.z * w4.z; acc[j][kc] += sv.w * w4.w;
      }
    }
  }
  const float b = bf1[fs * FS_ + f];
#pragma unroll
  for (int j = 0; j < 2; ++j) {
    float g = b;
    g += acc[j][0]; g += acc[j][1]; g += acc[j][2]; g += acc[j][3];
    g1l[(tg * 2 + j) * FS_ + f] = g;
  }
  __syncthreads();

  if (tid < FS_) {   // LIF scan over t (identical expressions)
    float v = 0.0f;
#pragma unroll
    for (int t = 0; t < T_; ++t) {
      const float g = g1l[t * FS_ + tid];
      v = v + (g - v) * 0.5f;
      const bool sp = (v >= 1.0f);
      h1[(t * N_ + n) * F1_ + fs * FS_ + tid] = sp ? 1.0f : 0.0f;
      v = sp ? 0.0f : v;
    }
  }
}

// -------- Kernel B: fused GEMM2 + bias + LIF scan + W_out pool + cumsum.
//          Weight strip staged in LDS in two k-halves (LDS budget ~87KB).
//          GS=16, 256 blocks. Last block per n finishes pool + cumsum. ----
__global__ __launch_bounds__(256) void kB_gemm2(const float* __restrict__ h1,
    const float* __restrict__ Wf2, const float* __restrict__ bf2,
    const float* __restrict__ Wout, const float* __restrict__ bout,
    float* __restrict__ partial, int* __restrict__ cnt, float* __restrict__ out) {
  __shared__ __align__(16) float h1l[T_ * 516];   // rows padded 512->516
  __shared__ __align__(16) float wl[GS_ * 260];   // W^T half-strip [g][k], pad
  __shared__ __align__(16) float g2l[T_ * GS_];
  __shared__ __align__(16) float h2l[T_ * GS_];
  __shared__ int lastFlag;
  const int bx = blockIdx.x;
  const int n = bx >> 4, gs = bx & 15;
  const int tid = threadIdx.x;

  {  // stage h1[:, n, :] -> LDS (float4, padded rows)
    const float4* g4 = (const float4*)h1;
    float4* l4 = (float4*)h1l;
#pragma unroll
    for (int r = 0; r < 16; ++r) {
      const int i4 = r * 256 + tid;
      const int t = i4 >> 7, fq = i4 & 127;
      l4[t * 129 + fq] = g4[(t * N_ + n) * 128 + fq];
    }
  }
  const int c4 = (tid & 3) << 2, kb = tid >> 2;   // kb 0..63
  {  // stage Wf2 k-half 0: k in [0,256) -> wl[g][k]
#pragma unroll
    for (int r = 0; r < 4; ++r) {
      const int k = r * 64 + kb;
      const float4 wv = *(const float4*)&Wf2[k * F2_ + gs * GS_ + c4];
      wl[(c4 + 0) * 260 + k] = wv.x;
      wl[(c4 + 1) * 260 + k] = wv.y;
      wl[(c4 + 2) * 260 + k] = wv.z;
      wl[(c4 + 3) * 260 + k] = wv.w;
    }
  }
  __syncthreads();

  const int g = tid & 15, tg = tid >> 4;
  float acc[2][8] = {};
#pragma unroll
  for (int kc = 0; kc < 4; ++kc) {   // chunks 0..3 (k-half 0), same FMA order
#pragma unroll
    for (int d0 = 0; d0 < 64; d0 += 4) {
      const float4 w4 = *(const float4*)&wl[g * 260 + kc * 64 + d0];
#pragma unroll
      for (int j = 0; j < 2; ++j) {
        const float4 hv = *(const float4*)&h1l[(tg * 2 + j) * 516 + kc * 64 + d0];
        acc[j][kc] += hv.x * w4.x; acc[j][kc] += hv.y * w4.y;
        acc[j][kc] += hv.z * w4.z; acc[j][kc] += hv.w * w4.w;
      }
    }
  }
  __syncthreads();   // all reads of wl half-0 done
  {  // stage Wf2 k-half 1: k in [256,512) -> wl[g][k-256]
#pragma unroll
    for (int r = 0; r < 4; ++r) {
      const int k = r * 64 + kb;
      const float4 wv = *(const float4*)&Wf2[(256 + k) * F2_ + gs * GS_ + c4];
      wl[(c4 + 0) * 260 + k] = wv.x;
      wl[(c4 + 1) * 260 + k] = wv.y;
      wl[(c4 + 2) * 260 + k] = wv.z;
      wl[(c4 + 3) * 260 + k] = wv.w;
    }
  }
  __syncthreads();
#pragma unroll
  for (int kc = 4; kc < 8; ++kc) {   // chunks 4..7 (k-half 1)
#pragma unroll
    for (int d0 = 0; d0 < 64; d0 += 4) {
      const float4 w4 = *(const float4*)&wl[g * 260 + (kc - 4) * 64 + d0];
#pragma unroll
      for (int j = 0; j < 2; ++j) {
        const float4 hv = *(const float4*)&h1l[(tg * 2 + j) * 516 + kc * 64 + d0];
        acc[j][kc] += hv.x * w4.x; acc[j][kc] += hv.y * w4.y;
        acc[j][kc] += hv.z * w4.z; acc[j][kc] += hv.w * w4.w;
      }
    }
  }

  const float b = bf2[gs * GS_ + g];
#pragma unroll
  for (int j = 0; j < 2; ++j) {
    float z = b;
#pragma unroll
    for (int kc = 0; kc < 8; ++kc) z += acc[j][kc];
    g2l[(tg * 2 + j) * GS_ + g] = z;
  }
  __syncthreads();

  if (tid < GS_) {   // LIF scan (identical expressions)
    float v = 0.0f;
#pragma unroll
    for (int t = 0; t < T_; ++t) {
      const float gv = g2l[t * GS_ + tid];
      v = v + (gv - v) * 0.5f;
      const bool sp = (v >= 1.0f);
      h2l[t * GS_ + tid] = sp ? 1.0f : 0.0f;
      v = sp ? 0.0f : v;
    }
  }
  __syncthreads();

  if (tid < T_) {    // per-strip partial pool (post-spike: reorder harmless)
    float pp = 0.0f;
#pragma unroll
    for (int j2 = 0; j2 < GS_; ++j2)
      pp += h2l[tid * GS_ + j2] * Wout[gs * GS_ + j2];
    __hip_atomic_fetch_add(&partial[tid * N_ + n], pp,
                           __ATOMIC_RELAXED, __HIP_MEMORY_SCOPE_AGENT);
  }
  __syncthreads();   // this block's atomics are issued & drained

  if (tid == 0) {
    __threadfence();
    const int old = __hip_atomic_fetch_add(&cnt[n], 1,
                        __ATOMIC_ACQ_REL, __HIP_MEMORY_SCOPE_AGENT);
    lastFlag = (old == 15);
  }
  __syncthreads();

  if (lastFlag && tid < T_) {  // last block for this n: finish pool + cumsum
    float val = __hip_atomic_load(&partial[tid * N_ + n],
                    __ATOMIC_RELAXED, __HIP_MEMORY_SCOPE_AGENT) + bout[0];
#pragma unroll
    for (int off = 1; off < 32; off <<= 1) {   // inclusive prefix over t
      const float up = __shfl_up(val, off, 64);
      if (tid >= off) val += up;
    }
    out[tid * N_ + n] = val;
  }
}

extern "C" void kernel_launch(void* const* d_in, const int* in_sizes, int n_in,
                              void* d_out, int out_size, void* d_ws, size_t ws_size,
                              hipStream_t stream) {
  (void)in_sizes; (void)n_in; (void)out_size; (void)ws_size;
  const float* x     = (const float*)d_in[0];
  const float* Wsdc  = (const float*)d_in[1];
  const float* bsdc  = (const float*)d_in[2];
  const float* wsyn  = (const float*)d_in[3];
  const float* Wpool = (const float*)d_in[4];
  const float* bpool = (const float*)d_in[5];
  const float* Wf1   = (const float*)d_in[6];
  const float* bf1   = (const float*)d_in[7];
  const float* Wf2   = (const float*)d_in[8];
  const float* bf2   = (const float*)d_in[9];
  const float* Wout  = (const float*)d_in[10];
  const float* bout  = (const float*)d_in[11];
  float* out = (float*)d_out;

  // ws layout (floats): s2[M*D] | h1[M*F1] | partial[T*N] | cnt[N]
  float* s2      = (float*)d_ws;
  float* h1      = s2 + M_ * D_;
  float* partial = h1 + M_ * F1_;
  int*   cnt     = (int*)(partial + T_ * N_);

  hipLaunchKernelGGL(k1_sdc, dim3(N_ * D_), dim3(64), 0, stream,
                     x, Wsdc, bsdc, wsyn, Wpool, bpool, s2);
  hipLaunchKernelGGL(kA_gemm1, dim3(N_ * (F1_ / FS_)), dim3(256), 0, stream,
                     s2, Wf1, bf1, h1, partial, cnt);
  hipLaunchKernelGGL(kB_gemm2, dim3(N_ * (F2_ / GS_)), dim3(256), 0, stream,
                     h1, Wf2, bf2, Wout, bout, partial, cnt, out);
}